// Round 2
// baseline (350.660 us; speedup 1.0000x reference)
//
#include <hip/hip_runtime.h>
#include <math.h>

// MHA fwd: B=8 H=16 T=1024 D=1024 dh=64. fp32 in/out, bf16 MFMA compute.
// Split-bf16 (hi+lo) 3-term MFMA for x@Wq, x@Wk and Q@K^T (logits sigma~1024
// need ~fp32 accuracy; 2-term and int8 variants fail the error budget).
// R1: S^T = K.Q^T formulation (softmax in-lane, P = A-frag of 16x16x16 MFMA).
// R2: Q/K/V frag-major panels + XCD swizzle (conflict-free LDS, L2 reuse).
// R3: V frag layout fused into V-GEMM epilogue.
// R4 FAILED: 512-thr launch_bounds(512,4) spilled P to scratch (343MB WRITE).
// R5: 64-key S chunking => no spill at (256,3).
// R6: attn K/V staging double-buffered; softmax tree-sum; fused transpose.
// R7: gemm_qk 256x256 / 8-wave / 4-phase counted-vmcnt schedule. Result:
//     conflicts 8.4M->0, VALUBusy 33->16, but MfmaUtil only 38.6% — each
//     phase's ds_reads issued AFTER the publishing barrier and immediately
//     consumed => 4 read-storms/tile of exposed LDS latency (~2200cyc).
// R8: single-barrier-per-K-tile schedule. Per tile: vmcnt(0)+barrier (stages
//     are a full tile old => ~0 wait), STAGE all 8 chunks of t+1, then issue
//     tile-t frag reads ahead of their MM clusters, liveness-ordered so only
//     the first quadrant's 12 reads are exposed (once per tile) and peak live
//     frag regs stay at 64 VGPR (a0+b0+b1 | a0+b1+a1lo | a1+b1+b0'):
//       RD a0,b0,b1 | MM(0,0) | RD a1[0:2] | MM(0,2) | RD a1[2:4],b0' |
//       MM(4,2) | MM(4,0)
//     All reads of a buffer are MFMA-consumed (compiler lgkm) before the
//     barrier that precedes overwriting stages => WAR safe with no extra sync.

typedef unsigned short u16;
typedef unsigned int u32;
typedef __bf16  bf16x8 __attribute__((ext_vector_type(8)));
typedef unsigned short u16x8 __attribute__((ext_vector_type(8)));
typedef unsigned short u16x4 __attribute__((ext_vector_type(4)));
typedef short s16x4 __attribute__((ext_vector_type(4)));
typedef unsigned int u32x2 __attribute__((ext_vector_type(2)));
typedef float f32x4 __attribute__((ext_vector_type(4)));

#define MFMA16(a,b,c) __builtin_amdgcn_mfma_f32_16x16x32_bf16((a),(b),(c),0,0,0)
#define MFMA16K16(a,b,c) __builtin_amdgcn_mfma_f32_16x16x16bf16_1k((a),(b),(c),0,0,0)

static __device__ __forceinline__ u16 f2b(float f){
  unsigned u = __builtin_bit_cast(unsigned, f);
  u += 0x7fffu + ((u >> 16) & 1u);            // RNE
  return (u16)(u >> 16);
}
static __device__ __forceinline__ float b2f(u16 h){
  unsigned u = ((unsigned)h) << 16;
  return __builtin_bit_cast(float, u);
}
static __device__ __forceinline__ bf16x8 ldsfrag(const u16* p){
  return __builtin_bit_cast(bf16x8, *(const u16x8*)p);
}
static __device__ __forceinline__ u32 packhi(float fa, float fb){
  return __builtin_amdgcn_perm(__builtin_bit_cast(u32, fa),
                               __builtin_bit_cast(u32, fb), 0x07060302u);
}
static __device__ __forceinline__ void gld16(const void* g, void* l){
  __builtin_amdgcn_global_load_lds(
      (const __attribute__((address_space(1))) void*)g,
      (__attribute__((address_space(3))) void*)l, 16, 0, 0);
}

// Frag-major panel conventions (u16 index), bh = b*16+h, tt = t&1023, d in [0,64):
//  K (A-frag of 16x16x32):  ktile=tt>>7 fkt=(tt>>4)&7 l15=tt&15 | kc=d>>5 q=(d>>3)&3 j=d&7
//    idx = (((bh*8+ktile)*8+fkt)*2+kc)*512 + (q*16+l15)*8 + j          [16KB/ktile]
//  Q (B-frag of 16x16x32):  qtile=tt>>7 r=tt&127 wv=r>>5 mt=(r>>4)&1 l15=tt&15
//    idx = ((((bh*8+qtile)*4+wv)*2+mt)*2+kc)*512 + (q*16+l15)*8 + j    [16KB/qtile]
//  V (B-frag of 16x16x16):  ktile=tt>>7 fkt=(tt>>4)&7 q=(tt>>2)&3 j=tt&3 | nd=d>>4 l15=d&15
//    idx = ((((bh*8+ktile)*8+fkt)*4+nd)*64 + q*16+l15)*4 + j           [16KB/ktile]
// 64-key granularity: tile j (0..15) of a bh = contiguous 4096-u16 block at
//   panel_base(bh) + j*4096 in each of K/Kl/V panels.

// ---------------- split x (fp32 -> hi/lo bf16) ----------------
__global__ __launch_bounds__(256) void split_x_kernel(
    const float* __restrict__ x, u16* __restrict__ xh, u16* __restrict__ xl, int n)
{
  int i = (blockIdx.x * 256 + threadIdx.x) * 8;
  if (i >= n) return;
  float4 v0 = *(const float4*)(x + i);
  float4 v1 = *(const float4*)(x + i + 4);
  float vv[8] = {v0.x, v0.y, v0.z, v0.w, v1.x, v1.y, v1.z, v1.w};
  u16x8 hv, lv;
#pragma unroll
  for (int j = 0; j < 8; j++){
    u16 hb = f2b(vv[j]);
    hv[j] = hb;
    lv[j] = f2b(vv[j] - b2f(hb));
  }
  *(u16x8*)(xh + i) = hv;
  *(u16x8*)(xl + i) = lv;
}

// ---------------- fused transpose of all 4 weights (z selects matrix) --------
__global__ __launch_bounds__(256) void transpose4_kernel(
    const float* __restrict__ Wq, const float* __restrict__ Wk,
    const float* __restrict__ Wv, const float* __restrict__ Wp,
    u16* __restrict__ qh_, u16* __restrict__ ql_,
    u16* __restrict__ kh_, u16* __restrict__ kl_,
    u16* __restrict__ vt_, u16* __restrict__ pt_)
{
  __shared__ float t[32][33];
  const int z = blockIdx.z;
  const float* W = (z == 0) ? Wq : (z == 1) ? Wk : (z == 2) ? Wv : Wp;
  u16* Th = (z == 0) ? qh_ : (z == 1) ? kh_ : (z == 2) ? vt_ : pt_;
  u16* Tl = (z == 0) ? ql_ : (z == 1) ? kl_ : nullptr;
  int n0 = blockIdx.x * 32, k0 = blockIdx.y * 32;
  int tx = threadIdx.x, ty = threadIdx.y;
#pragma unroll
  for (int i = 0; i < 4; i++){
    int k = k0 + ty + i * 8;
    t[ty + i * 8][tx] = W[(size_t)k * 1024 + n0 + tx];
  }
  __syncthreads();
#pragma unroll
  for (int i = 0; i < 4; i++){
    int n = n0 + ty + i * 8;
    float v = t[tx][ty + i * 8];
    u16 h = f2b(v);
    Th[(size_t)n * 1024 + k0 + tx] = h;
    if (Tl) Tl[(size_t)n * 1024 + k0 + tx] = f2b(v - b2f(h));
  }
}

// ---------------- plain bf16 GEMM: C = A * Bt^T ----------------
// OUTMODE 0: fp32 row-major C[M][N].  OUTMODE 2: bf16 V-frag panels (N=1024).
template<int OUTMODE>
__global__ __launch_bounds__(256) void gemm_bt_kernel(
    const u16* __restrict__ A, const u16* __restrict__ Bt, void* __restrict__ Cv,
    int M, int N, int K)
{
  __shared__ __attribute__((aligned(16))) u16 lA[4096], lB[4096];
  const int tid = threadIdx.x, lane = tid & 63, wave = tid >> 6;
  const int quad = lane >> 4, l15 = lane & 15;
  const int row0 = blockIdx.x * 128, col0 = blockIdx.y * 128;
  const int wm = wave >> 1, wn = wave & 1;
  const int sr = lane >> 2, sc = (lane & 3) * 8;
  f32x4 acc[4][4];
#pragma unroll
  for (int mt = 0; mt < 4; mt++)
#pragma unroll
    for (int nt = 0; nt < 4; nt++) acc[mt][nt] = (f32x4)0.0f;

  for (int k0 = 0; k0 < K; k0 += 32){
#pragma unroll
    for (int i = 0; i < 2; i++){
      int c = wave * 2 + i;
      gld16(A  + (size_t)(row0 + c * 16 + sr) * K + k0 + sc, &lA[c * 512]);
      gld16(Bt + (size_t)(col0 + c * 16 + sr) * K + k0 + sc, &lB[c * 512]);
    }
    __syncthreads();
    bf16x8 a[4], b[4];
#pragma unroll
    for (int t = 0; t < 4; t++){
      a[t] = ldsfrag(&lA[(wm * 64 + t * 16 + l15) * 32 + quad * 8]);
      b[t] = ldsfrag(&lB[(wn * 64 + t * 16 + l15) * 32 + quad * 8]);
    }
#pragma unroll
    for (int mt = 0; mt < 4; mt++)
#pragma unroll
      for (int nt = 0; nt < 4; nt++)
        acc[mt][nt] = MFMA16(a[mt], b[nt], acc[mt][nt]);
    __syncthreads();
  }
  if (OUTMODE == 2){
    // V-frag epilogue: j = r (contiguous) -> one u16x4 store per (mt,nt)
#pragma unroll
    for (int mt = 0; mt < 4; mt++)
#pragma unroll
      for (int nt = 0; nt < 4; nt++){
        int row = row0 + wm * 64 + mt * 16 + quad * 4;
        int col = col0 + wn * 64 + nt * 16 + l15;
        int bb = row >> 10, tt = row & 1023;
        int hh = (col >> 6) & 15, d = col & 63;
        int bhI = bb * 16 + hh;
        int ktile = tt >> 7, fkt = (tt >> 4) & 7, qF = (tt >> 2) & 3;
        int nd = d >> 4, l15F = d & 15;
        size_t idx = ((((size_t)(bhI * 8 + ktile) * 8 + fkt) * 4 + nd) * 64
                      + qF * 16 + l15F) * 4;
        u16x4 vals;
#pragma unroll
        for (int r = 0; r < 4; r++) vals[r] = f2b(acc[mt][nt][r]);
        *(u16x4*)(((u16*)Cv) + idx) = vals;
      }
  } else {
#pragma unroll
    for (int mt = 0; mt < 4; mt++)
#pragma unroll
      for (int nt = 0; nt < 4; nt++)
#pragma unroll
        for (int r = 0; r < 4; r++){
          int row = row0 + wm * 64 + mt * 16 + quad * 4 + r;
          int col = col0 + wn * 64 + nt * 16 + l15;
          ((float*)Cv)[(size_t)row * N + col] = acc[mt][nt][r];
        }
  }
}

// ---------------- 3-term split GEMM for Q||K projection -> frag-major panels ----
// R8 structure: 256x256 tile, 8 waves (wm=wave>>2 M, wn=wave&3 N), wave owns
// 128x64 of C (8x4 frags). BK=32, LDS 128KB double-buffered, frag-major via
// pre-permuted gld16 lanes (lane-linear ds_read_b128, 0 conflicts).
// ONE barrier + ONE vmcnt(0) per K-tile; stages a full tile old at the wait.
// Reads issued ahead of consuming MM clusters, liveness-ordered (peak 64
// frag VGPR). First quadrant's 12 reads are the only exposed LDS latency.
__global__ __launch_bounds__(512, 2) void gemm_qk_kernel(
    const u16* __restrict__ Ah, const u16* __restrict__ Al,
    const u16* __restrict__ Bh, const u16* __restrict__ Bl,
    u16* __restrict__ Qhf, u16* __restrict__ Qlf,
    u16* __restrict__ Khf, u16* __restrict__ Klf, int M, int N, int K)
{
  __shared__ __attribute__((aligned(16))) u16 sA[2][2][8192], sB[2][2][8192];
  const int tid = threadIdx.x, lane = tid & 63, wave = tid >> 6;
  const int quad = lane >> 4, l15 = lane & 15;
  const int wm = wave >> 2, wn = wave & 3;
  const int row0 = blockIdx.x * 256, col0 = blockIdx.y * 256;
  // staging: wave -> frag id per group; lane (quad,l15) -> (colblk,row) so the
  // 16B chunks land in LDS in exact A/B-fragment order (lane-linear reads).
  const int f0a = (wave & 3) | ((wave & 4) << 1);   // A-half0 frags {0-3,8-11}
  const int f0b = (wave & 1) | ((wave >> 1) << 2);  // B-half0 frags {0,1,4,5,8,9,12,13}
  const size_t fstride = (size_t)16 * K;
  const size_t abase = (size_t)(row0 + l15) * K + quad * 8;
  const size_t bbase = (size_t)(col0 + l15) * K + quad * 8;
  (void)M; (void)N;

  f32x4 acc[8][4];
#pragma unroll
  for (int mt = 0; mt < 8; mt++)
#pragma unroll
    for (int nt = 0; nt < 4; nt++) acc[mt][nt] = (f32x4)0.0f;

#define STAGE_ALL(KK, NB) do {                                                           \
    gld16(Ah + abase + (size_t)f0a * fstride + (KK), &sA[NB][0][f0a * 512]);             \
    gld16(Al + abase + (size_t)f0a * fstride + (KK), &sA[NB][1][f0a * 512]);             \
    gld16(Bh + bbase + (size_t)f0b * fstride + (KK), &sB[NB][0][f0b * 512]);             \
    gld16(Bl + bbase + (size_t)f0b * fstride + (KK), &sB[NB][1][f0b * 512]);             \
    gld16(Bh + bbase + (size_t)(f0b + 2) * fstride + (KK), &sB[NB][0][(f0b + 2) * 512]); \
    gld16(Bl + bbase + (size_t)(f0b + 2) * fstride + (KK), &sB[NB][1][(f0b + 2) * 512]); \
    gld16(Ah + abase + (size_t)(f0a + 4) * fstride + (KK), &sA[NB][0][(f0a + 4) * 512]); \
    gld16(Al + abase + (size_t)(f0a + 4) * fstride + (KK), &sA[NB][1][(f0a + 4) * 512]); \
  } while (0)
// read 2 A frag-pairs (B4+I0, B4+I0+1) into DH/DL[I0], [I0+1]
#define RD_A2(DH, DL, B4, I0, BUF) do {                           \
    _Pragma("unroll")                                             \
    for (int i = (I0); i < (I0) + 2; i++){                        \
      int fa = wm * 8 + (B4) + i;                                 \
      DH[i] = ldsfrag(&sA[BUF][0][fa * 512 + lane * 8]);          \
      DL[i] = ldsfrag(&sA[BUF][1][fa * 512 + lane * 8]);          \
    } } while (0)
// read 2 B frag-pairs (B2, B2+1) into DH/DL[0],[1]
#define RD_B2(DH, DL, B2, BUF) do {                               \
    _Pragma("unroll")                                             \
    for (int j = 0; j < 2; j++){                                  \
      int fb = wn * 4 + (B2) + j;                                 \
      DH[j] = ldsfrag(&sB[BUF][0][fb * 512 + lane * 8]);          \
      DL[j] = ldsfrag(&sB[BUF][1][fb * 512 + lane * 8]);          \
    } } while (0)
#define MM(AH, AL, BH, BL, M0, N0) do {                                      \
    __builtin_amdgcn_s_setprio(1);                                           \
    _Pragma("unroll")                                                        \
    for (int i = 0; i < 4; i++)                                              \
      _Pragma("unroll")                                                      \
      for (int j = 0; j < 2; j++){                                           \
        acc[(M0) + i][(N0) + j] = MFMA16(AL[i], BH[j], acc[(M0) + i][(N0) + j]); \
        acc[(M0) + i][(N0) + j] = MFMA16(AH[i], BL[j], acc[(M0) + i][(N0) + j]); \
        acc[(M0) + i][(N0) + j] = MFMA16(AH[i], BH[j], acc[(M0) + i][(N0) + j]); \
      }                                                                      \
    __builtin_amdgcn_s_setprio(0);                                           \
  } while (0)

  const int NT = K >> 5;
  // prologue: tile 0 into buf 0
  STAGE_ALL(0, 0);

  bf16x8 a0h[4], a0l[4], a1h[4], a1l[4];
  bf16x8 b0h[2], b0l[2], b1h[2], b1l[2];
#pragma unroll 2
  for (int t = 0; t < NT; t++){
    const int buf = t & 1, nb = buf ^ 1;
    const int kn = ((t + 1) & (NT - 1)) * 32;   // wrap on last tile
    asm volatile("s_waitcnt vmcnt(0)" ::: "memory");  // stages ~1 tile old
    asm volatile("s_barrier" ::: "memory");           // publish buf, WAR for nb
    STAGE_ALL(kn, nb);                                // issue t+1 early
    // tile-t reads, liveness-scheduled ahead of their MM clusters
    RD_A2(a0h, a0l, 0, 0, buf);
    RD_A2(a0h, a0l, 0, 2, buf);
    RD_B2(b0h, b0l, 0, buf);
    RD_B2(b1h, b1l, 2, buf);
    MM(a0h, a0l, b0h, b0l, 0, 0);     // quad (0,0); b0 dead after
    RD_A2(a1h, a1l, 4, 0, buf);       // hides under MM(0,2)
    MM(a0h, a0l, b1h, b1l, 0, 2);     // quad (0,1); a0 dead after
    RD_A2(a1h, a1l, 4, 2, buf);
    RD_B2(b0h, b0l, 0, buf);          // re-read B0 (reg reuse)
    MM(a1h, a1l, b1h, b1l, 4, 2);     // quad (1,1); b1 dead after
    MM(a1h, a1l, b0h, b0l, 4, 0);     // quad (1,0)
  }
  asm volatile("s_waitcnt vmcnt(0)" ::: "memory");  // drain wrap-prefetch

#undef STAGE_ALL
#undef RD_A2
#undef RD_B2
#undef MM

  const bool isQ = (col0 < 1024);
#pragma unroll
  for (int mt = 0; mt < 8; mt++)
#pragma unroll
    for (int nt = 0; nt < 4; nt++)
#pragma unroll
      for (int r = 0; r < 4; r++){
        int row = row0 + wm * 128 + mt * 16 + quad * 4 + r;
        int col = col0 + wn * 64 + nt * 16 + l15;
        int bb = row >> 10, tt = row & 1023;
        int hh = (col >> 6) & 15, d = col & 63;
        int bhI = bb * 16 + hh;
        int kc = d >> 5, qF = (d >> 3) & 3, j = d & 7;
        float v = acc[mt][nt][r];
        u16 hi = f2b(v);
        u16 lo = f2b(v - b2f(hi));
        if (isQ){
          int qtile = tt >> 7, rr = tt & 127;
          int wv = rr >> 5, mtF = (rr >> 4) & 1, l15F = tt & 15;
          size_t idx = ((((size_t)(bhI * 8 + qtile) * 4 + wv) * 2 + mtF) * 2 + kc) * 512
                       + (qF * 16 + l15F) * 8 + j;
          Qhf[idx] = hi; Qlf[idx] = lo;
        } else {
          int ktile = tt >> 7, fkt = (tt >> 4) & 7, l15F = tt & 15;
          size_t idx = (((size_t)(bhI * 8 + ktile) * 8 + fkt) * 2 + kc) * 512
                       + (qF * 16 + l15F) * 8 + j;
          Khf[idx] = hi; Klf[idx] = lo;
        }
      }
}

// ---------------- flash attention (S^T, frag-major, 64-key dbuf tiles) -------
// grid = 1024, block = 256 (4 waves x 32 q-rows). qt = bid>>7, bh = bid&127
// (same-bh blocks 128 apart => same XCD => K/V L2-shared).
// 16 tiles of 64 keys; LDS double-buffered (2 x 24KB); barrier THEN prefetch
// order so each barrier's vmcnt(0) drain finds tile j's loads one full
// compute phase old.
__global__ __launch_bounds__(256, 3) void attn_kernel(
    const u16* __restrict__ Qhf, const u16* __restrict__ Qlf,
    const u16* __restrict__ Khf, const u16* __restrict__ Klf,
    const u16* __restrict__ Vf, u16* __restrict__ O)
{
  __shared__ __attribute__((aligned(16))) u16 lKh[2][4096], lKl[2][4096], lV[2][4096];
  const int tid = threadIdx.x, lane = tid & 63, wave = tid >> 6;
  const int quad = lane >> 4, l15 = lane & 15;
  const int qt = blockIdx.x >> 7, bh = blockIdx.x & 127;
  const int b = bh >> 4, h = bh & 15;
  const int q0 = qt * 128;
  const float BETA = 0.18033688011112042f;   // (1/sqrt(64)) * log2(e)

  bf16x8 qh[2][2], ql[2][2];
  { // stage Q through the (not-yet-used) double buffers as 16KB scratch
    size_t qbase = (size_t)(bh * 8 + qt) * 8192 + wave * 2048 + lane * 8;
    u16* sh = &lKh[0][0];  u16* sl = &lKl[0][0];   // flattened 2x4096
#pragma unroll
    for (int i = 0; i < 4; i++){
      gld16(Qhf + qbase + i * 512, sh + wave * 2048 + i * 512);
      gld16(Qlf + qbase + i * 512, sl + wave * 2048 + i * 512);
    }
    __syncthreads();
#pragma unroll
    for (int mt = 0; mt < 2; mt++)
#pragma unroll
      for (int kc = 0; kc < 2; kc++){
        int off = wave * 2048 + (mt * 2 + kc) * 512 + lane * 8;
        qh[mt][kc] = ldsfrag(sh + off);
        ql[mt][kc] = ldsfrag(sl + off);
      }
    __syncthreads();
  }

  float m_i[2] = {-3.0e38f, -3.0e38f}, l_i[2] = {0.0f, 0.0f};
  f32x4 o_acc[2][4];
#pragma unroll
  for (int mt = 0; mt < 2; mt++)
#pragma unroll
    for (int nd = 0; nd < 4; nd++) o_acc[mt][nd] = (f32x4)0.0f;

  const size_t pan = (size_t)bh * 65536;   // per-bh K/Kl/V panel base (u16)
  // prefetch tile 0 into buf 0 (2 chunks per array per wave)
#pragma unroll
  for (int i = 0; i < 2; i++){
    int c = wave * 2 + i;                  // 0..7 chunks of 512 u16
    gld16(Khf + pan + c * 512 + lane * 8, &lKh[0][c * 512]);
    gld16(Klf + pan + c * 512 + lane * 8, &lKl[0][c * 512]);
    gld16(Vf  + pan + c * 512 + lane * 8, &lV [0][c * 512]);
  }

#pragma unroll 1
  for (int j = 0; j < 16; j++){
    const int cur = j & 1;
    __syncthreads();                       // drains tile-j loads (1 phase old)
    if (j < 15){
      size_t nb = pan + (size_t)(j + 1) * 4096;
      const int nxt = cur ^ 1;
#pragma unroll
      for (int i = 0; i < 2; i++){
        int c = wave * 2 + i;
        gld16(Khf + nb + c * 512 + lane * 8, &lKh[nxt][c * 512]);
        gld16(Klf + nb + c * 512 + lane * 8, &lKl[nxt][c * 512]);
        gld16(Vf  + nb + c * 512 + lane * 8, &lV [nxt][c * 512]);
      }
    }

    // S^T = K.Q^T for 64 keys (A = K frags, B = Q frags), 3-term split
    f32x4 s[2][4];
#pragma unroll
    for (int qt2 = 0; qt2 < 2; qt2++)
#pragma unroll
      for (int f4 = 0; f4 < 4; f4++) s[qt2][f4] = (f32x4)0.0f;
#pragma unroll
    for (int f4 = 0; f4 < 4; f4++){
      int aoff = f4 * 1024 + lane * 8;     // lane-linear, conflict-free
      bf16x8 kh0 = ldsfrag(&lKh[cur][aoff]);
      bf16x8 kh1 = ldsfrag(&lKh[cur][aoff + 512]);
      bf16x8 kl0 = ldsfrag(&lKl[cur][aoff]);
      bf16x8 kl1 = ldsfrag(&lKl[cur][aoff + 512]);
#pragma unroll
      for (int qt2 = 0; qt2 < 2; qt2++){
        s[qt2][f4] = MFMA16(kl0, qh[qt2][0], s[qt2][f4]);
        s[qt2][f4] = MFMA16(kl1, qh[qt2][1], s[qt2][f4]);
        s[qt2][f4] = MFMA16(kh0, ql[qt2][0], s[qt2][f4]);
        s[qt2][f4] = MFMA16(kh1, ql[qt2][1], s[qt2][f4]);
        s[qt2][f4] = MFMA16(kh0, qh[qt2][0], s[qt2][f4]);
        s[qt2][f4] = MFMA16(kh1, qh[qt2][1], s[qt2][f4]);
      }
    }

    // online softmax merge (lane l15 = q; 16 logits in-lane)
    float alpha[2];
#pragma unroll
    for (int qt2 = 0; qt2 < 2; qt2++){
      f32x4 mv = s[qt2][0];
#pragma unroll
      for (int f4 = 1; f4 < 4; f4++){
        mv[0] = fmaxf(mv[0], s[qt2][f4][0]); mv[1] = fmaxf(mv[1], s[qt2][f4][1]);
        mv[2] = fmaxf(mv[2], s[qt2][f4][2]); mv[3] = fmaxf(mv[3], s[qt2][f4][3]);
      }
      float mx = fmaxf(fmaxf(mv[0], mv[1]), fmaxf(mv[2], mv[3]));
      mx = fmaxf(mx, __shfl_xor(mx, 16));
      mx = fmaxf(mx, __shfl_xor(mx, 32));
      float mn = fmaxf(m_i[qt2], mx);
      alpha[qt2] = __builtin_amdgcn_exp2f((m_i[qt2] - mn) * BETA);
      m_i[qt2] = mn;
      float mb = mn * BETA;
      f32x4 ps = (f32x4)0.0f;
#pragma unroll
      for (int f4 = 0; f4 < 4; f4++)
#pragma unroll
        for (int r = 0; r < 4; r++){
          float p = __builtin_amdgcn_exp2f(s[qt2][f4][r] * BETA - mb);
          s[qt2][f4][r] = p;
          ps[r] += p;                      // 4 independent partial chains
        }
      float rs = (ps[0] + ps[1]) + (ps[2] + ps[3]);
      rs += __shfl_xor(rs, 16);
      rs += __shfl_xor(rs, 32);
      l_i[qt2] = l_i[qt2] * alpha[qt2] + rs;
    }

    // rescale O (alpha at lane l15=q -> broadcast to O row layout)
#pragma unroll
    for (int mt = 0; mt < 2; mt++)
#pragma unroll
      for (int r = 0; r < 4; r++){
        float ar = __shfl(alpha[mt], quad * 4 + r);
#pragma unroll
        for (int nd = 0; nd < 4; nd++) o_acc[mt][nd][r] *= ar;
      }

    // PV via 16x16x16 MFMA; P already in A-frag layout; V lane-linear b64
#pragma unroll
    for (int f4 = 0; f4 < 4; f4++){
      s16x4 vb[4];
#pragma unroll
      for (int nd = 0; nd < 4; nd++)
        vb[nd] = __builtin_bit_cast(s16x4,
                   *(const u16x4*)&lV[cur][(f4 * 4 + nd) * 256 + lane * 4]);
#pragma unroll
      for (int qt2 = 0; qt2 < 2; qt2++){
        u32x2 pd;
        pd[0] = packhi(s[qt2][f4][1], s[qt2][f4][0]);
        pd[1] = packhi(s[qt2][f4][3], s[qt2][f4][2]);
        s16x4 pa = __builtin_bit_cast(s16x4, pd);
#pragma unroll
        for (int nd = 0; nd < 4; nd++)
          o_acc[qt2][nd] = MFMA16K16(pa, vb[nd], o_acc[qt2][nd]);
      }
    }
  }

#pragma unroll
  for (int mt = 0; mt < 2; mt++)
#pragma unroll
    for (int r = 0; r < 4; r++){
      float lr = __shfl(l_i[mt], quad * 4 + r);
      float inv = 1.0f / lr;
      int t = q0 + wave * 32 + mt * 16 + quad * 4 + r;
      size_t rowoff = (size_t)(b * 1024 + t) * 1024 + h * 64;
#pragma unroll
      for (int nd = 0; nd < 4; nd++)
        O[rowoff + nd * 16 + l15] = f2b(o_acc[mt][nd][r] * inv);
    }
}

// ---------------- launcher ----------------
extern "C" void kernel_launch(void* const* d_in, const int* in_sizes, int n_in,
                              void* d_out, int out_size, void* d_ws, size_t ws_size,
                              hipStream_t stream)
{
  const float* x  = (const float*)d_in[0];
  const float* Wq = (const float*)d_in[1];
  const float* Wk = (const float*)d_in[2];
  const float* Wv = (const float*)d_in[3];
  const float* Wp = (const float*)d_in[4];
  float* out = (float*)d_out;
  char* ws = (char*)d_ws;
  const size_t MB = 1024 * 1024;
  // workspace map (peak 124 MB):
  u16* xh   = (u16*)(ws + 0);        // 16MB; reused as O after V-GEMM
  u16* xl   = (u16*)(ws + 16 * MB);  // 16MB
  u16* wqkh = (u16*)(ws + 32 * MB);  // 4MB  [2048][1024]
  u16* wqkl = (u16*)(ws + 36 * MB);  // 4MB
  u16* wvt  = (u16*)(ws + 40 * MB);  // 2MB
  u16* wpt  = (u16*)(ws + 42 * MB);  // 2MB
  u16* Qhf  = (u16*)(ws + 44 * MB);  // 16MB frag-major Q hi
  u16* Qlf  = (u16*)(ws + 60 * MB);  // 16MB frag-major Q lo
  u16* Khf  = (u16*)(ws + 76 * MB);  // 16MB frag-major K hi
  u16* Klf  = (u16*)(ws + 92 * MB);  // 16MB frag-major K lo
  u16* Vf   = (u16*)(ws + 108 * MB); // 16MB frag-major V
  u16* obuf = xh;
  (void)in_sizes; (void)n_in; (void)out_size; (void)ws_size;

  split_x_kernel<<<4096, 256, 0, stream>>>(x, xh, xl, 8 * 1024 * 1024);
  transpose4_kernel<<<dim3(32, 32, 4), dim3(32, 8), 0, stream>>>(
      Wq, Wk, Wv, Wp, wqkh, wqkl, wqkh + 1024 * 1024, wqkl + 1024 * 1024, wvt, wpt);
  gemm_qk_kernel<<<dim3(32, 8), 512, 0, stream>>>(xh, xl, wqkh, wqkl,
                                                  Qhf, Qlf, Khf, Klf, 8192, 2048, 1024);
  gemm_bt_kernel<2><<<dim3(64, 8), 256, 0, stream>>>(xh, wvt, (void*)Vf, 8192, 1024, 1024);
  attn_kernel<<<1024, 256, 0, stream>>>(Qhf, Qlf, Khf, Klf, Vf, obuf);
  gemm_bt_kernel<0><<<dim3(64, 8), 256, 0, stream>>>(obuf, wpt, (void*)out, 8192, 1024, 1024);
}

// Round 3
// 340.028 us; speedup vs baseline: 1.0313x; 1.0313x over previous
//
#include <hip/hip_runtime.h>
#include <math.h>

// MHA fwd: B=8 H=16 T=1024 D=1024 dh=64. fp32 in/out, bf16 MFMA compute.
// Split-bf16 (hi+lo) 3-term MFMA for x@Wq, x@Wk and Q@K^T (logits sigma~1024
// need ~fp32 accuracy; 2-term and int8 variants fail the error budget).
// R1: S^T = K.Q^T formulation (softmax in-lane, P = A-frag of 16x16x16 MFMA).
// R2: Q/K/V frag-major panels + XCD swizzle (conflict-free LDS, L2 reuse).
// R3: V frag layout fused into V-GEMM epilogue.
// R4 FAILED: 512-thr launch_bounds(512,4) spilled P to scratch (343MB WRITE).
// R5: 64-key S chunking => no spill at (256,3).
// R6: attn K/V staging double-buffered; softmax tree-sum; fused transpose.
// R7: gemm_qk 256x256 / 8-wave / 4-phase counted-vmcnt. 125->112us, conflicts
//     8.4M->0, but MfmaUtil 38.6%: reads-after-barrier => 4 storms/tile.
// R8 FAILED (128.9us): single-barrier tile body let the 2 waves/SIMD drift;
//     one wave alone can't fill the MFMA pipe (3-dep-chain MM), so the pipe
//     ran half-fed. Barriers were not the cost - de-phasing was.
// R9: m201-faithful phase shape: publish whole tile once (vmcnt(0)+bar at
//     tile top, loads a full tile old), then 4 phases of
//     {RD quadrant ; STAGE 2-4 ; s_barrier ; setprio MFMA x24}.
//     Reads of phases 1-3 issue before their phase-lock barrier (overlap the
//     previous MFMA tail across waves); only phase 0's 12-read storm is
//     exposed, once per tile. 5 barriers/tile, waves stay phase-locked.

typedef unsigned short u16;
typedef unsigned int u32;
typedef __bf16  bf16x8 __attribute__((ext_vector_type(8)));
typedef unsigned short u16x8 __attribute__((ext_vector_type(8)));
typedef unsigned short u16x4 __attribute__((ext_vector_type(4)));
typedef short s16x4 __attribute__((ext_vector_type(4)));
typedef unsigned int u32x2 __attribute__((ext_vector_type(2)));
typedef float f32x4 __attribute__((ext_vector_type(4)));

#define MFMA16(a,b,c) __builtin_amdgcn_mfma_f32_16x16x32_bf16((a),(b),(c),0,0,0)
#define MFMA16K16(a,b,c) __builtin_amdgcn_mfma_f32_16x16x16bf16_1k((a),(b),(c),0,0,0)

static __device__ __forceinline__ u16 f2b(float f){
  unsigned u = __builtin_bit_cast(unsigned, f);
  u += 0x7fffu + ((u >> 16) & 1u);            // RNE
  return (u16)(u >> 16);
}
static __device__ __forceinline__ float b2f(u16 h){
  unsigned u = ((unsigned)h) << 16;
  return __builtin_bit_cast(float, u);
}
static __device__ __forceinline__ bf16x8 ldsfrag(const u16* p){
  return __builtin_bit_cast(bf16x8, *(const u16x8*)p);
}
static __device__ __forceinline__ u32 packhi(float fa, float fb){
  return __builtin_amdgcn_perm(__builtin_bit_cast(u32, fa),
                               __builtin_bit_cast(u32, fb), 0x07060302u);
}
static __device__ __forceinline__ void gld16(const void* g, void* l){
  __builtin_amdgcn_global_load_lds(
      (const __attribute__((address_space(1))) void*)g,
      (__attribute__((address_space(3))) void*)l, 16, 0, 0);
}

// Frag-major panel conventions (u16 index), bh = b*16+h, tt = t&1023, d in [0,64):
//  K (A-frag of 16x16x32):  ktile=tt>>7 fkt=(tt>>4)&7 l15=tt&15 | kc=d>>5 q=(d>>3)&3 j=d&7
//    idx = (((bh*8+ktile)*8+fkt)*2+kc)*512 + (q*16+l15)*8 + j          [16KB/ktile]
//  Q (B-frag of 16x16x32):  qtile=tt>>7 r=tt&127 wv=r>>5 mt=(r>>4)&1 l15=tt&15
//    idx = ((((bh*8+qtile)*4+wv)*2+mt)*2+kc)*512 + (q*16+l15)*8 + j    [16KB/qtile]
//  V (B-frag of 16x16x16):  ktile=tt>>7 fkt=(tt>>4)&7 q=(tt>>2)&3 j=tt&3 | nd=d>>4 l15=d&15
//    idx = ((((bh*8+ktile)*8+fkt)*4+nd)*64 + q*16+l15)*4 + j           [16KB/ktile]
// 64-key granularity: tile j (0..15) of a bh = contiguous 4096-u16 block at
//   panel_base(bh) + j*4096 in each of K/Kl/V panels.

// ---------------- split x (fp32 -> hi/lo bf16) ----------------
__global__ __launch_bounds__(256) void split_x_kernel(
    const float* __restrict__ x, u16* __restrict__ xh, u16* __restrict__ xl, int n)
{
  int i = (blockIdx.x * 256 + threadIdx.x) * 8;
  if (i >= n) return;
  float4 v0 = *(const float4*)(x + i);
  float4 v1 = *(const float4*)(x + i + 4);
  float vv[8] = {v0.x, v0.y, v0.z, v0.w, v1.x, v1.y, v1.z, v1.w};
  u16x8 hv, lv;
#pragma unroll
  for (int j = 0; j < 8; j++){
    u16 hb = f2b(vv[j]);
    hv[j] = hb;
    lv[j] = f2b(vv[j] - b2f(hb));
  }
  *(u16x8*)(xh + i) = hv;
  *(u16x8*)(xl + i) = lv;
}

// ---------------- fused transpose of all 4 weights (z selects matrix) --------
__global__ __launch_bounds__(256) void transpose4_kernel(
    const float* __restrict__ Wq, const float* __restrict__ Wk,
    const float* __restrict__ Wv, const float* __restrict__ Wp,
    u16* __restrict__ qh_, u16* __restrict__ ql_,
    u16* __restrict__ kh_, u16* __restrict__ kl_,
    u16* __restrict__ vt_, u16* __restrict__ pt_)
{
  __shared__ float t[32][33];
  const int z = blockIdx.z;
  const float* W = (z == 0) ? Wq : (z == 1) ? Wk : (z == 2) ? Wv : Wp;
  u16* Th = (z == 0) ? qh_ : (z == 1) ? kh_ : (z == 2) ? vt_ : pt_;
  u16* Tl = (z == 0) ? ql_ : (z == 1) ? kl_ : nullptr;
  int n0 = blockIdx.x * 32, k0 = blockIdx.y * 32;
  int tx = threadIdx.x, ty = threadIdx.y;
#pragma unroll
  for (int i = 0; i < 4; i++){
    int k = k0 + ty + i * 8;
    t[ty + i * 8][tx] = W[(size_t)k * 1024 + n0 + tx];
  }
  __syncthreads();
#pragma unroll
  for (int i = 0; i < 4; i++){
    int n = n0 + ty + i * 8;
    float v = t[tx][ty + i * 8];
    u16 h = f2b(v);
    Th[(size_t)n * 1024 + k0 + tx] = h;
    if (Tl) Tl[(size_t)n * 1024 + k0 + tx] = f2b(v - b2f(h));
  }
}

// ---------------- plain bf16 GEMM: C = A * Bt^T ----------------
// OUTMODE 0: fp32 row-major C[M][N].  OUTMODE 2: bf16 V-frag panels (N=1024).
template<int OUTMODE>
__global__ __launch_bounds__(256) void gemm_bt_kernel(
    const u16* __restrict__ A, const u16* __restrict__ Bt, void* __restrict__ Cv,
    int M, int N, int K)
{
  __shared__ __attribute__((aligned(16))) u16 lA[4096], lB[4096];
  const int tid = threadIdx.x, lane = tid & 63, wave = tid >> 6;
  const int quad = lane >> 4, l15 = lane & 15;
  const int row0 = blockIdx.x * 128, col0 = blockIdx.y * 128;
  const int wm = wave >> 1, wn = wave & 1;
  const int sr = lane >> 2, sc = (lane & 3) * 8;
  f32x4 acc[4][4];
#pragma unroll
  for (int mt = 0; mt < 4; mt++)
#pragma unroll
    for (int nt = 0; nt < 4; nt++) acc[mt][nt] = (f32x4)0.0f;

  for (int k0 = 0; k0 < K; k0 += 32){
#pragma unroll
    for (int i = 0; i < 2; i++){
      int c = wave * 2 + i;
      gld16(A  + (size_t)(row0 + c * 16 + sr) * K + k0 + sc, &lA[c * 512]);
      gld16(Bt + (size_t)(col0 + c * 16 + sr) * K + k0 + sc, &lB[c * 512]);
    }
    __syncthreads();
    bf16x8 a[4], b[4];
#pragma unroll
    for (int t = 0; t < 4; t++){
      a[t] = ldsfrag(&lA[(wm * 64 + t * 16 + l15) * 32 + quad * 8]);
      b[t] = ldsfrag(&lB[(wn * 64 + t * 16 + l15) * 32 + quad * 8]);
    }
#pragma unroll
    for (int mt = 0; mt < 4; mt++)
#pragma unroll
      for (int nt = 0; nt < 4; nt++)
        acc[mt][nt] = MFMA16(a[mt], b[nt], acc[mt][nt]);
    __syncthreads();
  }
  if (OUTMODE == 2){
    // V-frag epilogue: j = r (contiguous) -> one u16x4 store per (mt,nt)
#pragma unroll
    for (int mt = 0; mt < 4; mt++)
#pragma unroll
      for (int nt = 0; nt < 4; nt++){
        int row = row0 + wm * 64 + mt * 16 + quad * 4;
        int col = col0 + wn * 64 + nt * 16 + l15;
        int bb = row >> 10, tt = row & 1023;
        int hh = (col >> 6) & 15, d = col & 63;
        int bhI = bb * 16 + hh;
        int ktile = tt >> 7, fkt = (tt >> 4) & 7, qF = (tt >> 2) & 3;
        int nd = d >> 4, l15F = d & 15;
        size_t idx = ((((size_t)(bhI * 8 + ktile) * 8 + fkt) * 4 + nd) * 64
                      + qF * 16 + l15F) * 4;
        u16x4 vals;
#pragma unroll
        for (int r = 0; r < 4; r++) vals[r] = f2b(acc[mt][nt][r]);
        *(u16x4*)(((u16*)Cv) + idx) = vals;
      }
  } else {
#pragma unroll
    for (int mt = 0; mt < 4; mt++)
#pragma unroll
      for (int nt = 0; nt < 4; nt++)
#pragma unroll
        for (int r = 0; r < 4; r++){
          int row = row0 + wm * 64 + mt * 16 + quad * 4 + r;
          int col = col0 + wn * 64 + nt * 16 + l15;
          ((float*)Cv)[(size_t)row * N + col] = acc[mt][nt][r];
        }
  }
}

// ---------------- 3-term split GEMM for Q||K projection -> frag-major panels ----
// R9 structure: 256x256 tile, 8 waves (wm=wave>>2 M, wn=wave&3 N), wave owns
// 128x64 of C (8x4 frags). BK=32, LDS 128KB double-buffered, frag-major via
// pre-permuted gld16 lanes (lane-linear ds_read_b128, 0 conflicts).
// Tile top: vmcnt(0)+barrier publishes buf (stages are a full tile old).
// Then 4 phase-locked phases {RD ; STAGE ; s_barrier ; setprio MFMA x24}:
// phases 1-3's reads issue before their barrier (overlap other waves' MFMA
// tail); only phase 0's 12-read storm is exposed, once per tile.
__global__ __launch_bounds__(512, 2) void gemm_qk_kernel(
    const u16* __restrict__ Ah, const u16* __restrict__ Al,
    const u16* __restrict__ Bh, const u16* __restrict__ Bl,
    u16* __restrict__ Qhf, u16* __restrict__ Qlf,
    u16* __restrict__ Khf, u16* __restrict__ Klf, int M, int N, int K)
{
  __shared__ __attribute__((aligned(16))) u16 sA[2][2][8192], sB[2][2][8192];
  const int tid = threadIdx.x, lane = tid & 63, wave = tid >> 6;
  const int quad = lane >> 4, l15 = lane & 15;
  const int wm = wave >> 2, wn = wave & 3;
  const int row0 = blockIdx.x * 256, col0 = blockIdx.y * 256;
  // staging: wave -> frag id per group; lane (quad,l15) -> (colblk,row) so the
  // 16B chunks land in LDS in exact A/B-fragment order (lane-linear reads).
  const int f0a = (wave & 3) | ((wave & 4) << 1);   // A-half0 frags {0-3,8-11}
  const int f0b = (wave & 1) | ((wave >> 1) << 2);  // B-half0 frags {0,1,4,5,8,9,12,13}
  const size_t fstride = (size_t)16 * K;
  const size_t abase = (size_t)(row0 + l15) * K + quad * 8;
  const size_t bbase = (size_t)(col0 + l15) * K + quad * 8;
  (void)M; (void)N;

  f32x4 acc[8][4];
#pragma unroll
  for (int mt = 0; mt < 8; mt++)
#pragma unroll
    for (int nt = 0; nt < 4; nt++) acc[mt][nt] = (f32x4)0.0f;

#define STAGE_G0(KK, NB) do {                                              \
    gld16(Ah + abase + (size_t)f0a * fstride + (KK), &sA[NB][0][f0a * 512]); \
    gld16(Al + abase + (size_t)f0a * fstride + (KK), &sA[NB][1][f0a * 512]); \
    gld16(Bh + bbase + (size_t)f0b * fstride + (KK), &sB[NB][0][f0b * 512]); \
    gld16(Bl + bbase + (size_t)f0b * fstride + (KK), &sB[NB][1][f0b * 512]); \
  } while (0)
#define STAGE_G1(KK, NB) do {                                                        \
    gld16(Bh + bbase + (size_t)(f0b + 2) * fstride + (KK), &sB[NB][0][(f0b + 2) * 512]); \
    gld16(Bl + bbase + (size_t)(f0b + 2) * fstride + (KK), &sB[NB][1][(f0b + 2) * 512]); \
  } while (0)
#define STAGE_G2(KK, NB) do {                                                        \
    gld16(Ah + abase + (size_t)(f0a + 4) * fstride + (KK), &sA[NB][0][(f0a + 4) * 512]); \
    gld16(Al + abase + (size_t)(f0a + 4) * fstride + (KK), &sA[NB][1][(f0a + 4) * 512]); \
  } while (0)
// read 2 A frag-pairs (B4+I0, B4+I0+1) into DH/DL[I0], [I0+1]
#define RD_A2(DH, DL, B4, I0, BUF) do {                           \
    _Pragma("unroll")                                             \
    for (int i = (I0); i < (I0) + 2; i++){                        \
      int fa = wm * 8 + (B4) + i;                                 \
      DH[i] = ldsfrag(&sA[BUF][0][fa * 512 + lane * 8]);          \
      DL[i] = ldsfrag(&sA[BUF][1][fa * 512 + lane * 8]);          \
    } } while (0)
// read 2 B frag-pairs (B2, B2+1) into DH/DL[0],[1]
#define RD_B2(DH, DL, B2, BUF) do {                               \
    _Pragma("unroll")                                             \
    for (int j = 0; j < 2; j++){                                  \
      int fb = wn * 4 + (B2) + j;                                 \
      DH[j] = ldsfrag(&sB[BUF][0][fb * 512 + lane * 8]);          \
      DL[j] = ldsfrag(&sB[BUF][1][fb * 512 + lane * 8]);          \
    } } while (0)
#define MM(AH, AL, BH, BL, M0, N0) do {                                      \
    __builtin_amdgcn_s_setprio(1);                                           \
    _Pragma("unroll")                                                        \
    for (int i = 0; i < 4; i++)                                              \
      _Pragma("unroll")                                                      \
      for (int j = 0; j < 2; j++){                                           \
        acc[(M0) + i][(N0) + j] = MFMA16(AL[i], BH[j], acc[(M0) + i][(N0) + j]); \
        acc[(M0) + i][(N0) + j] = MFMA16(AH[i], BL[j], acc[(M0) + i][(N0) + j]); \
        acc[(M0) + i][(N0) + j] = MFMA16(AH[i], BH[j], acc[(M0) + i][(N0) + j]); \
      }                                                                      \
    __builtin_amdgcn_s_setprio(0);                                           \
  } while (0)
#define VMCNT0() asm volatile("s_waitcnt vmcnt(0)" ::: "memory")
#define BARRIER() asm volatile("s_barrier" ::: "memory")

  const int NT = K >> 5;
  // prologue: tile 0 into buf 0
  STAGE_G0(0, 0);
  STAGE_G1(0, 0);
  STAGE_G2(0, 0);

  bf16x8 a0h[4], a0l[4], a1h[4], a1l[4];
  bf16x8 b0h[2], b0l[2], b1h[2], b1l[2];
#pragma unroll 2
  for (int t = 0; t < NT; t++){
    const int buf = t & 1, nb = buf ^ 1;
    const int kn = ((t + 1) & (NT - 1)) * 32;   // wrap on last tile
    VMCNT0();                          // stages a full tile old => ~free
    BARRIER();                         // publish buf; WAR fence for nb
    // ---- phase 0: quadrant (A-half0, B-half0) — only exposed read storm
    RD_A2(a0h, a0l, 0, 0, buf);
    RD_A2(a0h, a0l, 0, 2, buf);
    RD_B2(b0h, b0l, 0, buf);
    STAGE_G0(kn, nb);
    BARRIER();                         // phase-lock
    MM(a0h, a0l, b0h, b0l, 0, 0);
    // ---- phase 1: quadrant (A-half0, B-half1) — A regs reused
    RD_B2(b1h, b1l, 2, buf);
    STAGE_G1(kn, nb);
    BARRIER();
    MM(a0h, a0l, b1h, b1l, 0, 2);
    // ---- phase 2: quadrant (A-half1, B-half1) — B regs reused
    RD_A2(a1h, a1l, 4, 0, buf);
    RD_A2(a1h, a1l, 4, 2, buf);
    STAGE_G2(kn, nb);
    BARRIER();
    MM(a1h, a1l, b1h, b1l, 4, 2);
    // ---- phase 3: quadrant (A-half1, B-half0) — re-read B0
    RD_B2(b0h, b0l, 0, buf);
    BARRIER();
    MM(a1h, a1l, b0h, b0l, 4, 0);
  }
  VMCNT0();                            // drain wrap-prefetch

#undef STAGE_G0
#undef STAGE_G1
#undef STAGE_G2
#undef RD_A2
#undef RD_B2
#undef MM
#undef VMCNT0
#undef BARRIER

  const bool isQ = (col0 < 1024);
#pragma unroll
  for (int mt = 0; mt < 8; mt++)
#pragma unroll
    for (int nt = 0; nt < 4; nt++)
#pragma unroll
      for (int r = 0; r < 4; r++){
        int row = row0 + wm * 128 + mt * 16 + quad * 4 + r;
        int col = col0 + wn * 64 + nt * 16 + l15;
        int bb = row >> 10, tt = row & 1023;
        int hh = (col >> 6) & 15, d = col & 63;
        int bhI = bb * 16 + hh;
        int kc = d >> 5, qF = (d >> 3) & 3, j = d & 7;
        float v = acc[mt][nt][r];
        u16 hi = f2b(v);
        u16 lo = f2b(v - b2f(hi));
        if (isQ){
          int qtile = tt >> 7, rr = tt & 127;
          int wv = rr >> 5, mtF = (rr >> 4) & 1, l15F = tt & 15;
          size_t idx = ((((size_t)(bhI * 8 + qtile) * 4 + wv) * 2 + mtF) * 2 + kc) * 512
                       + (qF * 16 + l15F) * 8 + j;
          Qhf[idx] = hi; Qlf[idx] = lo;
        } else {
          int ktile = tt >> 7, fkt = (tt >> 4) & 7, l15F = tt & 15;
          size_t idx = (((size_t)(bhI * 8 + ktile) * 8 + fkt) * 2 + kc) * 512
                       + (qF * 16 + l15F) * 8 + j;
          Khf[idx] = hi; Klf[idx] = lo;
        }
      }
}

// ---------------- flash attention (S^T, frag-major, 64-key dbuf tiles) -------
// grid = 1024, block = 256 (4 waves x 32 q-rows). qt = bid>>7, bh = bid&127
// (same-bh blocks 128 apart => same XCD => K/V L2-shared).
// 16 tiles of 64 keys; LDS double-buffered (2 x 24KB); barrier THEN prefetch
// order so each barrier's vmcnt(0) drain finds tile j's loads one full
// compute phase old.
__global__ __launch_bounds__(256, 3) void attn_kernel(
    const u16* __restrict__ Qhf, const u16* __restrict__ Qlf,
    const u16* __restrict__ Khf, const u16* __restrict__ Klf,
    const u16* __restrict__ Vf, u16* __restrict__ O)
{
  __shared__ __attribute__((aligned(16))) u16 lKh[2][4096], lKl[2][4096], lV[2][4096];
  const int tid = threadIdx.x, lane = tid & 63, wave = tid >> 6;
  const int quad = lane >> 4, l15 = lane & 15;
  const int qt = blockIdx.x >> 7, bh = blockIdx.x & 127;
  const int b = bh >> 4, h = bh & 15;
  const int q0 = qt * 128;
  const float BETA = 0.18033688011112042f;   // (1/sqrt(64)) * log2(e)

  bf16x8 qh[2][2], ql[2][2];
  { // stage Q through the (not-yet-used) double buffers as 16KB scratch
    size_t qbase = (size_t)(bh * 8 + qt) * 8192 + wave * 2048 + lane * 8;
    u16* sh = &lKh[0][0];  u16* sl = &lKl[0][0];   // flattened 2x4096
#pragma unroll
    for (int i = 0; i < 4; i++){
      gld16(Qhf + qbase + i * 512, sh + wave * 2048 + i * 512);
      gld16(Qlf + qbase + i * 512, sl + wave * 2048 + i * 512);
    }
    __syncthreads();
#pragma unroll
    for (int mt = 0; mt < 2; mt++)
#pragma unroll
      for (int kc = 0; kc < 2; kc++){
        int off = wave * 2048 + (mt * 2 + kc) * 512 + lane * 8;
        qh[mt][kc] = ldsfrag(sh + off);
        ql[mt][kc] = ldsfrag(sl + off);
      }
    __syncthreads();
  }

  float m_i[2] = {-3.0e38f, -3.0e38f}, l_i[2] = {0.0f, 0.0f};
  f32x4 o_acc[2][4];
#pragma unroll
  for (int mt = 0; mt < 2; mt++)
#pragma unroll
    for (int nd = 0; nd < 4; nd++) o_acc[mt][nd] = (f32x4)0.0f;

  const size_t pan = (size_t)bh * 65536;   // per-bh K/Kl/V panel base (u16)
  // prefetch tile 0 into buf 0 (2 chunks per array per wave)
#pragma unroll
  for (int i = 0; i < 2; i++){
    int c = wave * 2 + i;                  // 0..7 chunks of 512 u16
    gld16(Khf + pan + c * 512 + lane * 8, &lKh[0][c * 512]);
    gld16(Klf + pan + c * 512 + lane * 8, &lKl[0][c * 512]);
    gld16(Vf  + pan + c * 512 + lane * 8, &lV [0][c * 512]);
  }

#pragma unroll 1
  for (int j = 0; j < 16; j++){
    const int cur = j & 1;
    __syncthreads();                       // drains tile-j loads (1 phase old)
    if (j < 15){
      size_t nb = pan + (size_t)(j + 1) * 4096;
      const int nxt = cur ^ 1;
#pragma unroll
      for (int i = 0; i < 2; i++){
        int c = wave * 2 + i;
        gld16(Khf + nb + c * 512 + lane * 8, &lKh[nxt][c * 512]);
        gld16(Klf + nb + c * 512 + lane * 8, &lKl[nxt][c * 512]);
        gld16(Vf  + nb + c * 512 + lane * 8, &lV [nxt][c * 512]);
      }
    }

    // S^T = K.Q^T for 64 keys (A = K frags, B = Q frags), 3-term split
    f32x4 s[2][4];
#pragma unroll
    for (int qt2 = 0; qt2 < 2; qt2++)
#pragma unroll
      for (int f4 = 0; f4 < 4; f4++) s[qt2][f4] = (f32x4)0.0f;
#pragma unroll
    for (int f4 = 0; f4 < 4; f4++){
      int aoff = f4 * 1024 + lane * 8;     // lane-linear, conflict-free
      bf16x8 kh0 = ldsfrag(&lKh[cur][aoff]);
      bf16x8 kh1 = ldsfrag(&lKh[cur][aoff + 512]);
      bf16x8 kl0 = ldsfrag(&lKl[cur][aoff]);
      bf16x8 kl1 = ldsfrag(&lKl[cur][aoff + 512]);
#pragma unroll
      for (int qt2 = 0; qt2 < 2; qt2++){
        s[qt2][f4] = MFMA16(kl0, qh[qt2][0], s[qt2][f4]);
        s[qt2][f4] = MFMA16(kl1, qh[qt2][1], s[qt2][f4]);
        s[qt2][f4] = MFMA16(kh0, ql[qt2][0], s[qt2][f4]);
        s[qt2][f4] = MFMA16(kh1, ql[qt2][1], s[qt2][f4]);
        s[qt2][f4] = MFMA16(kh0, qh[qt2][0], s[qt2][f4]);
        s[qt2][f4] = MFMA16(kh1, qh[qt2][1], s[qt2][f4]);
      }
    }

    // online softmax merge (lane l15 = q; 16 logits in-lane)
    float alpha[2];
#pragma unroll
    for (int qt2 = 0; qt2 < 2; qt2++){
      f32x4 mv = s[qt2][0];
#pragma unroll
      for (int f4 = 1; f4 < 4; f4++){
        mv[0] = fmaxf(mv[0], s[qt2][f4][0]); mv[1] = fmaxf(mv[1], s[qt2][f4][1]);
        mv[2] = fmaxf(mv[2], s[qt2][f4][2]); mv[3] = fmaxf(mv[3], s[qt2][f4][3]);
      }
      float mx = fmaxf(fmaxf(mv[0], mv[1]), fmaxf(mv[2], mv[3]));
      mx = fmaxf(mx, __shfl_xor(mx, 16));
      mx = fmaxf(mx, __shfl_xor(mx, 32));
      float mn = fmaxf(m_i[qt2], mx);
      alpha[qt2] = __builtin_amdgcn_exp2f((m_i[qt2] - mn) * BETA);
      m_i[qt2] = mn;
      float mb = mn * BETA;
      f32x4 ps = (f32x4)0.0f;
#pragma unroll
      for (int f4 = 0; f4 < 4; f4++)
#pragma unroll
        for (int r = 0; r < 4; r++){
          float p = __builtin_amdgcn_exp2f(s[qt2][f4][r] * BETA - mb);
          s[qt2][f4][r] = p;
          ps[r] += p;                      // 4 independent partial chains
        }
      float rs = (ps[0] + ps[1]) + (ps[2] + ps[3]);
      rs += __shfl_xor(rs, 16);
      rs += __shfl_xor(rs, 32);
      l_i[qt2] = l_i[qt2] * alpha[qt2] + rs;
    }

    // rescale O (alpha at lane l15=q -> broadcast to O row layout)
#pragma unroll
    for (int mt = 0; mt < 2; mt++)
#pragma unroll
      for (int r = 0; r < 4; r++){
        float ar = __shfl(alpha[mt], quad * 4 + r);
#pragma unroll
        for (int nd = 0; nd < 4; nd++) o_acc[mt][nd][r] *= ar;
      }

    // PV via 16x16x16 MFMA; P already in A-frag layout; V lane-linear b64
#pragma unroll
    for (int f4 = 0; f4 < 4; f4++){
      s16x4 vb[4];
#pragma unroll
      for (int nd = 0; nd < 4; nd++)
        vb[nd] = __builtin_bit_cast(s16x4,
                   *(const u16x4*)&lV[cur][(f4 * 4 + nd) * 256 + lane * 4]);
#pragma unroll
      for (int qt2 = 0; qt2 < 2; qt2++){
        u32x2 pd;
        pd[0] = packhi(s[qt2][f4][1], s[qt2][f4][0]);
        pd[1] = packhi(s[qt2][f4][3], s[qt2][f4][2]);
        s16x4 pa = __builtin_bit_cast(s16x4, pd);
#pragma unroll
        for (int nd = 0; nd < 4; nd++)
          o_acc[qt2][nd] = MFMA16K16(pa, vb[nd], o_acc[qt2][nd]);
      }
    }
  }

#pragma unroll
  for (int mt = 0; mt < 2; mt++)
#pragma unroll
    for (int r = 0; r < 4; r++){
      float lr = __shfl(l_i[mt], quad * 4 + r);
      float inv = 1.0f / lr;
      int t = q0 + wave * 32 + mt * 16 + quad * 4 + r;
      size_t rowoff = (size_t)(b * 1024 + t) * 1024 + h * 64;
#pragma unroll
      for (int nd = 0; nd < 4; nd++)
        O[rowoff + nd * 16 + l15] = f2b(o_acc[mt][nd][r] * inv);
    }
}

// ---------------- launcher ----------------
extern "C" void kernel_launch(void* const* d_in, const int* in_sizes, int n_in,
                              void* d_out, int out_size, void* d_ws, size_t ws_size,
                              hipStream_t stream)
{
  const float* x  = (const float*)d_in[0];
  const float* Wq = (const float*)d_in[1];
  const float* Wk = (const float*)d_in[2];
  const float* Wv = (const float*)d_in[3];
  const float* Wp = (const float*)d_in[4];
  float* out = (float*)d_out;
  char* ws = (char*)d_ws;
  const size_t MB = 1024 * 1024;
  // workspace map (peak 124 MB):
  u16* xh   = (u16*)(ws + 0);        // 16MB; reused as O after V-GEMM
  u16* xl   = (u16*)(ws + 16 * MB);  // 16MB
  u16* wqkh = (u16*)(ws + 32 * MB);  // 4MB  [2048][1024]
  u16* wqkl = (u16*)(ws + 36 * MB);  // 4MB
  u16* wvt  = (u16*)(ws + 40 * MB);  // 2MB
  u16* wpt  = (u16*)(ws + 42 * MB);  // 2MB
  u16* Qhf  = (u16*)(ws + 44 * MB);  // 16MB frag-major Q hi
  u16* Qlf  = (u16*)(ws + 60 * MB);  // 16MB frag-major Q lo
  u16* Khf  = (u16*)(ws + 76 * MB);  // 16MB frag-major K hi
  u16* Klf  = (u16*)(ws + 92 * MB);  // 16MB frag-major K lo
  u16* Vf   = (u16*)(ws + 108 * MB); // 16MB frag-major V
  u16* obuf = xh;
  (void)in_sizes; (void)n_in; (void)out_size; (void)ws_size;

  split_x_kernel<<<4096, 256, 0, stream>>>(x, xh, xl, 8 * 1024 * 1024);
  transpose4_kernel<<<dim3(32, 32, 4), dim3(32, 8), 0, stream>>>(
      Wq, Wk, Wv, Wp, wqkh, wqkl, wqkh + 1024 * 1024, wqkl + 1024 * 1024, wvt, wpt);
  gemm_qk_kernel<<<dim3(32, 8), 512, 0, stream>>>(xh, xl, wqkh, wqkl,
                                                  Qhf, Qlf, Khf, Klf, 8192, 2048, 1024);
  gemm_bt_kernel<2><<<dim3(64, 8), 256, 0, stream>>>(xh, wvt, (void*)Vf, 8192, 1024, 1024);
  attn_kernel<<<1024, 256, 0, stream>>>(Qhf, Qlf, Khf, Klf, Vf, obuf);
  gemm_bt_kernel<0><<<dim3(64, 8), 256, 0, stream>>>(obuf, wpt, (void*)out, 8192, 1024, 1024);
}

// Round 5
// 333.989 us; speedup vs baseline: 1.0499x; 1.0181x over previous
//
#include <hip/hip_runtime.h>
#include <math.h>

// MHA fwd: B=8 H=16 T=1024 D=1024 dh=64. fp32 in/out, bf16 MFMA compute.
// Split-bf16 (hi+lo) 3-term MFMA for x@Wq, x@Wk and Q@K^T (logits sigma~1024
// need ~fp32 accuracy; 2-term and int8 variants fail the error budget).
// R1: S^T = K.Q^T formulation (softmax in-lane, P = A-frag of 16x16x16 MFMA).
// R2: Q/K/V frag-major panels + XCD swizzle (conflict-free LDS, L2 reuse).
// R3: V frag layout fused into V-GEMM epilogue.
// R4 FAILED: 512-thr launch_bounds(512,4) spilled P to scratch (343MB WRITE).
// R5: 64-key S chunking => no spill at (256,3).
// R6: attn K/V staging double-buffered; softmax tree-sum; fused transpose.
// R7: gemm_qk 256x256 / 8-wave / 4-phase counted-vmcnt. 125->112.5us,
//     conflicts 8.4M->0, VALUBusy 33->16, MfmaUtil 38.6%.
// R8 FAILED (128.9us): single-barrier tile body let the 2 waves/SIMD drift;
//     one wave alone can't fill the MFMA pipe. De-phasing was the cost.
// R9 FAILED (121.2us): 5-barrier full phase-lock, reads before phase barrier.
//     Phase-locked reads overlap nothing (all waves read+wait together) and
//     2 extra barriers/tile cost more than R7's read storms.
// R10: revert to R7 structure (best measured) + term-major MM: emit all 8
//     accs' term-1 MFMAs, then term-2, then term-3. Guarantees >=155cyc
//     between dependent MFMAs on the same acc regardless of compiler
//     scheduling (was 3 back-to-back dependent MFMAs per acc). Per-acc
//     accumulation order unchanged => bit-identical numerics.
//     (Round 4 bench was an infra failure - container died; resubmitted.)

typedef unsigned short u16;
typedef unsigned int u32;
typedef __bf16  bf16x8 __attribute__((ext_vector_type(8)));
typedef unsigned short u16x8 __attribute__((ext_vector_type(8)));
typedef unsigned short u16x4 __attribute__((ext_vector_type(4)));
typedef short s16x4 __attribute__((ext_vector_type(4)));
typedef unsigned int u32x2 __attribute__((ext_vector_type(2)));
typedef float f32x4 __attribute__((ext_vector_type(4)));

#define MFMA16(a,b,c) __builtin_amdgcn_mfma_f32_16x16x32_bf16((a),(b),(c),0,0,0)
#define MFMA16K16(a,b,c) __builtin_amdgcn_mfma_f32_16x16x16bf16_1k((a),(b),(c),0,0,0)

static __device__ __forceinline__ u16 f2b(float f){
  unsigned u = __builtin_bit_cast(unsigned, f);
  u += 0x7fffu + ((u >> 16) & 1u);            // RNE
  return (u16)(u >> 16);
}
static __device__ __forceinline__ float b2f(u16 h){
  unsigned u = ((unsigned)h) << 16;
  return __builtin_bit_cast(float, u);
}
static __device__ __forceinline__ bf16x8 ldsfrag(const u16* p){
  return __builtin_bit_cast(bf16x8, *(const u16x8*)p);
}
static __device__ __forceinline__ u32 packhi(float fa, float fb){
  return __builtin_amdgcn_perm(__builtin_bit_cast(u32, fa),
                               __builtin_bit_cast(u32, fb), 0x07060302u);
}
static __device__ __forceinline__ void gld16(const void* g, void* l){
  __builtin_amdgcn_global_load_lds(
      (const __attribute__((address_space(1))) void*)g,
      (__attribute__((address_space(3))) void*)l, 16, 0, 0);
}

// Frag-major panel conventions (u16 index), bh = b*16+h, tt = t&1023, d in [0,64):
//  K (A-frag of 16x16x32):  ktile=tt>>7 fkt=(tt>>4)&7 l15=tt&15 | kc=d>>5 q=(d>>3)&3 j=d&7
//    idx = (((bh*8+ktile)*8+fkt)*2+kc)*512 + (q*16+l15)*8 + j          [16KB/ktile]
//  Q (B-frag of 16x16x32):  qtile=tt>>7 r=tt&127 wv=r>>5 mt=(r>>4)&1 l15=tt&15
//    idx = ((((bh*8+qtile)*4+wv)*2+mt)*2+kc)*512 + (q*16+l15)*8 + j    [16KB/qtile]
//  V (B-frag of 16x16x16):  ktile=tt>>7 fkt=(tt>>4)&7 q=(tt>>2)&3 j=tt&3 | nd=d>>4 l15=d&15
//    idx = ((((bh*8+ktile)*8+fkt)*4+nd)*64 + q*16+l15)*4 + j           [16KB/ktile]
// 64-key granularity: tile j (0..15) of a bh = contiguous 4096-u16 block at
//   panel_base(bh) + j*4096 in each of K/Kl/V panels.

// ---------------- split x (fp32 -> hi/lo bf16) ----------------
__global__ __launch_bounds__(256) void split_x_kernel(
    const float* __restrict__ x, u16* __restrict__ xh, u16* __restrict__ xl, int n)
{
  int i = (blockIdx.x * 256 + threadIdx.x) * 8;
  if (i >= n) return;
  float4 v0 = *(const float4*)(x + i);
  float4 v1 = *(const float4*)(x + i + 4);
  float vv[8] = {v0.x, v0.y, v0.z, v0.w, v1.x, v1.y, v1.z, v1.w};
  u16x8 hv, lv;
#pragma unroll
  for (int j = 0; j < 8; j++){
    u16 hb = f2b(vv[j]);
    hv[j] = hb;
    lv[j] = f2b(vv[j] - b2f(hb));
  }
  *(u16x8*)(xh + i) = hv;
  *(u16x8*)(xl + i) = lv;
}

// ---------------- fused transpose of all 4 weights (z selects matrix) --------
__global__ __launch_bounds__(256) void transpose4_kernel(
    const float* __restrict__ Wq, const float* __restrict__ Wk,
    const float* __restrict__ Wv, const float* __restrict__ Wp,
    u16* __restrict__ qh_, u16* __restrict__ ql_,
    u16* __restrict__ kh_, u16* __restrict__ kl_,
    u16* __restrict__ vt_, u16* __restrict__ pt_)
{
  __shared__ float t[32][33];
  const int z = blockIdx.z;
  const float* W = (z == 0) ? Wq : (z == 1) ? Wk : (z == 2) ? Wv : Wp;
  u16* Th = (z == 0) ? qh_ : (z == 1) ? kh_ : (z == 2) ? vt_ : pt_;
  u16* Tl = (z == 0) ? ql_ : (z == 1) ? kl_ : nullptr;
  int n0 = blockIdx.x * 32, k0 = blockIdx.y * 32;
  int tx = threadIdx.x, ty = threadIdx.y;
#pragma unroll
  for (int i = 0; i < 4; i++){
    int k = k0 + ty + i * 8;
    t[ty + i * 8][tx] = W[(size_t)k * 1024 + n0 + tx];
  }
  __syncthreads();
#pragma unroll
  for (int i = 0; i < 4; i++){
    int n = n0 + ty + i * 8;
    float v = t[tx][ty + i * 8];
    u16 h = f2b(v);
    Th[(size_t)n * 1024 + k0 + tx] = h;
    if (Tl) Tl[(size_t)n * 1024 + k0 + tx] = f2b(v - b2f(h));
  }
}

// ---------------- plain bf16 GEMM: C = A * Bt^T ----------------
// OUTMODE 0: fp32 row-major C[M][N].  OUTMODE 2: bf16 V-frag panels (N=1024).
template<int OUTMODE>
__global__ __launch_bounds__(256) void gemm_bt_kernel(
    const u16* __restrict__ A, const u16* __restrict__ Bt, void* __restrict__ Cv,
    int M, int N, int K)
{
  __shared__ __attribute__((aligned(16))) u16 lA[4096], lB[4096];
  const int tid = threadIdx.x, lane = tid & 63, wave = tid >> 6;
  const int quad = lane >> 4, l15 = lane & 15;
  const int row0 = blockIdx.x * 128, col0 = blockIdx.y * 128;
  const int wm = wave >> 1, wn = wave & 1;
  const int sr = lane >> 2, sc = (lane & 3) * 8;
  f32x4 acc[4][4];
#pragma unroll
  for (int mt = 0; mt < 4; mt++)
#pragma unroll
    for (int nt = 0; nt < 4; nt++) acc[mt][nt] = (f32x4)0.0f;

  for (int k0 = 0; k0 < K; k0 += 32){
#pragma unroll
    for (int i = 0; i < 2; i++){
      int c = wave * 2 + i;
      gld16(A  + (size_t)(row0 + c * 16 + sr) * K + k0 + sc, &lA[c * 512]);
      gld16(Bt + (size_t)(col0 + c * 16 + sr) * K + k0 + sc, &lB[c * 512]);
    }
    __syncthreads();
    bf16x8 a[4], b[4];
#pragma unroll
    for (int t = 0; t < 4; t++){
      a[t] = ldsfrag(&lA[(wm * 64 + t * 16 + l15) * 32 + quad * 8]);
      b[t] = ldsfrag(&lB[(wn * 64 + t * 16 + l15) * 32 + quad * 8]);
    }
#pragma unroll
    for (int mt = 0; mt < 4; mt++)
#pragma unroll
      for (int nt = 0; nt < 4; nt++)
        acc[mt][nt] = MFMA16(a[mt], b[nt], acc[mt][nt]);
    __syncthreads();
  }
  if (OUTMODE == 2){
    // V-frag epilogue: j = r (contiguous) -> one u16x4 store per (mt,nt)
#pragma unroll
    for (int mt = 0; mt < 4; mt++)
#pragma unroll
      for (int nt = 0; nt < 4; nt++){
        int row = row0 + wm * 64 + mt * 16 + quad * 4;
        int col = col0 + wn * 64 + nt * 16 + l15;
        int bb = row >> 10, tt = row & 1023;
        int hh = (col >> 6) & 15, d = col & 63;
        int bhI = bb * 16 + hh;
        int ktile = tt >> 7, fkt = (tt >> 4) & 7, qF = (tt >> 2) & 3;
        int nd = d >> 4, l15F = d & 15;
        size_t idx = ((((size_t)(bhI * 8 + ktile) * 8 + fkt) * 4 + nd) * 64
                      + qF * 16 + l15F) * 4;
        u16x4 vals;
#pragma unroll
        for (int r = 0; r < 4; r++) vals[r] = f2b(acc[mt][nt][r]);
        *(u16x4*)(((u16*)Cv) + idx) = vals;
      }
  } else {
#pragma unroll
    for (int mt = 0; mt < 4; mt++)
#pragma unroll
      for (int nt = 0; nt < 4; nt++)
#pragma unroll
        for (int r = 0; r < 4; r++){
          int row = row0 + wm * 64 + mt * 16 + quad * 4 + r;
          int col = col0 + wn * 64 + nt * 16 + l15;
          ((float*)Cv)[(size_t)row * N + col] = acc[mt][nt][r];
        }
  }
}

// ---------------- 3-term split GEMM for Q||K projection -> frag-major panels ----
// R10 = R7 structure: 256x256 tile, 8 waves (wm=wave>>2 M, wn=wave&3 N), wave
// owns 128x64 of C (8x4 frags). BK=32, LDS 128KB double-buffered, frag-major
// via pre-permuted gld16 lanes (lane-linear ds_read_b128, 0 conflicts).
// Phases per K-tile (quadrant order (0,0)(0,1)(1,1)(1,0)):
//   p0: vmcnt(4) bar | rdA0 rdB0 | issue G0(t+1) | mfma 24
//   p1: vmcnt(6) bar | rdB1      | issue G1(t+1) | mfma 24   (A regs reused)
//   p2: vmcnt(6) bar | rdA1      | issue G2(t+1) | mfma 24   (B regs reused)
//   p3:              | rdB0      |               | mfma 24   (no barrier)
// MM is term-major (8 term-1 MFMAs, 8 term-2, 8 term-3) for guaranteed
// dep spacing. Last tile wrap-prefetches tile 0; post-loop vmcnt(0) drain.
__global__ __launch_bounds__(512, 2) void gemm_qk_kernel(
    const u16* __restrict__ Ah, const u16* __restrict__ Al,
    const u16* __restrict__ Bh, const u16* __restrict__ Bl,
    u16* __restrict__ Qhf, u16* __restrict__ Qlf,
    u16* __restrict__ Khf, u16* __restrict__ Klf, int M, int N, int K)
{
  __shared__ __attribute__((aligned(16))) u16 sA[2][2][8192], sB[2][2][8192];
  const int tid = threadIdx.x, lane = tid & 63, wave = tid >> 6;
  const int quad = lane >> 4, l15 = lane & 15;
  const int wm = wave >> 2, wn = wave & 3;
  const int row0 = blockIdx.x * 256, col0 = blockIdx.y * 256;
  // staging: wave -> frag id per group; lane (quad,l15) -> (colblk,row) so the
  // 16B chunks land in LDS in exact A/B-fragment order (lane-linear reads).
  const int f0a = (wave & 3) | ((wave & 4) << 1);   // A-half0 frags {0-3,8-11}
  const int f0b = (wave & 1) | ((wave >> 1) << 2);  // B-half0 frags {0,1,4,5,8,9,12,13}
  const size_t fstride = (size_t)16 * K;
  const size_t abase = (size_t)(row0 + l15) * K + quad * 8;
  const size_t bbase = (size_t)(col0 + l15) * K + quad * 8;
  (void)M; (void)N;

  f32x4 acc[8][4];
#pragma unroll
  for (int mt = 0; mt < 8; mt++)
#pragma unroll
    for (int nt = 0; nt < 4; nt++) acc[mt][nt] = (f32x4)0.0f;

#define STAGE_G0(KK, NB) do {                                              \
    gld16(Ah + abase + (size_t)f0a * fstride + (KK), &sA[NB][0][f0a * 512]); \
    gld16(Al + abase + (size_t)f0a * fstride + (KK), &sA[NB][1][f0a * 512]); \
    gld16(Bh + bbase + (size_t)f0b * fstride + (KK), &sB[NB][0][f0b * 512]); \
    gld16(Bl + bbase + (size_t)f0b * fstride + (KK), &sB[NB][1][f0b * 512]); \
  } while (0)
#define STAGE_G1(KK, NB) do {                                                        \
    gld16(Bh + bbase + (size_t)(f0b + 2) * fstride + (KK), &sB[NB][0][(f0b + 2) * 512]); \
    gld16(Bl + bbase + (size_t)(f0b + 2) * fstride + (KK), &sB[NB][1][(f0b + 2) * 512]); \
  } while (0)
#define STAGE_G2(KK, NB) do {                                                        \
    gld16(Ah + abase + (size_t)(f0a + 4) * fstride + (KK), &sA[NB][0][(f0a + 4) * 512]); \
    gld16(Al + abase + (size_t)(f0a + 4) * fstride + (KK), &sA[NB][1][(f0a + 4) * 512]); \
  } while (0)
#define RD_A(B4, BUF) do {                                        \
    _Pragma("unroll")                                             \
    for (int i = 0; i < 4; i++){                                  \
      int fa = wm * 8 + (B4) + i;                                 \
      ahf[i] = ldsfrag(&sA[BUF][0][fa * 512 + lane * 8]);         \
      alf[i] = ldsfrag(&sA[BUF][1][fa * 512 + lane * 8]);         \
    } } while (0)
#define RD_B(B2, BUF) do {                                        \
    _Pragma("unroll")                                             \
    for (int j = 0; j < 2; j++){                                  \
      int fb = wn * 4 + (B2) + j;                                 \
      bhf[j] = ldsfrag(&sB[BUF][0][fb * 512 + lane * 8]);         \
      blf[j] = ldsfrag(&sB[BUF][1][fb * 512 + lane * 8]);         \
    } } while (0)
// term-major: all 8 accs' term-1, then term-2, then term-3. Per-acc order
// unchanged (al*bh, ah*bl, ah*bh) => identical numerics, max dep spacing.
#define MM(M0, N0) do {                                                      \
    __builtin_amdgcn_s_setprio(1);                                           \
    _Pragma("unroll")                                                        \
    for (int i = 0; i < 4; i++)                                              \
      _Pragma("unroll")                                                      \
      for (int j = 0; j < 2; j++)                                            \
        acc[(M0) + i][(N0) + j] = MFMA16(alf[i], bhf[j], acc[(M0) + i][(N0) + j]); \
    _Pragma("unroll")                                                        \
    for (int i = 0; i < 4; i++)                                              \
      _Pragma("unroll")                                                      \
      for (int j = 0; j < 2; j++)                                            \
        acc[(M0) + i][(N0) + j] = MFMA16(ahf[i], blf[j], acc[(M0) + i][(N0) + j]); \
    _Pragma("unroll")                                                        \
    for (int i = 0; i < 4; i++)                                              \
      _Pragma("unroll")                                                      \
      for (int j = 0; j < 2; j++)                                            \
        acc[(M0) + i][(N0) + j] = MFMA16(ahf[i], bhf[j], acc[(M0) + i][(N0) + j]); \
    __builtin_amdgcn_s_setprio(0);                                           \
  } while (0)
#define VMCNT4() asm volatile("s_waitcnt vmcnt(4)" ::: "memory")
#define VMCNT6() asm volatile("s_waitcnt vmcnt(6)" ::: "memory")
#define BARRIER() asm volatile("s_barrier" ::: "memory")

  const int NT = K >> 5;
  // prologue: tile 0 into buf 0, in group order (g0 oldest)
  STAGE_G0(0, 0);
  STAGE_G1(0, 0);
  STAGE_G2(0, 0);

  bf16x8 ahf[4], alf[4], bhf[2], blf[2];
#pragma unroll 2
  for (int t = 0; t < NT; t++){
    const int buf = t & 1, nb = buf ^ 1;
    const int kn = ((t + 1) & (NT - 1)) * 32;   // wrap on last tile
    // phase 0: quadrant (A-half0, B-half0)
    VMCNT4();              // completes G0(t): exactly A-half0 + B-half0
    BARRIER();
    RD_A(0, buf);
    RD_B(0, buf);
    STAGE_G0(kn, nb);
    MM(0, 0);
    // phase 1: quadrant (A-half0, B-half1) — A regs reused
    VMCNT6();              // completes G1(t): B-half1
    BARRIER();
    RD_B(2, buf);
    STAGE_G1(kn, nb);
    MM(0, 2);
    // phase 2: quadrant (A-half1, B-half1) — B regs reused
    VMCNT6();              // completes G2(t): A-half1
    BARRIER();
    RD_A(4, buf);
    STAGE_G2(kn, nb);
    MM(4, 2);
    // phase 3: quadrant (A-half1, B-half0) — everything resident, no barrier
    RD_B(0, buf);
    MM(4, 0);
  }
  asm volatile("s_waitcnt vmcnt(0)" ::: "memory");  // drain wrap-prefetch

#undef STAGE_G0
#undef STAGE_G1
#undef STAGE_G2
#undef RD_A
#undef RD_B
#undef MM
#undef VMCNT4
#undef VMCNT6
#undef BARRIER

  const bool isQ = (col0 < 1024);
#pragma unroll
  for (int mt = 0; mt < 8; mt++)
#pragma unroll
    for (int nt = 0; nt < 4; nt++)
#pragma unroll
      for (int r = 0; r < 4; r++){
        int row = row0 + wm * 128 + mt * 16 + quad * 4 + r;
        int col = col0 + wn * 64 + nt * 16 + l15;
        int bb = row >> 10, tt = row & 1023;
        int hh = (col >> 6) & 15, d = col & 63;
        int bhI = bb * 16 + hh;
        int kc = d >> 5, qF = (d >> 3) & 3, j = d & 7;
        float v = acc[mt][nt][r];
        u16 hi = f2b(v);
        u16 lo = f2b(v - b2f(hi));
        if (isQ){
          int qtile = tt >> 7, rr = tt & 127;
          int wv = rr >> 5, mtF = (rr >> 4) & 1, l15F = tt & 15;
          size_t idx = ((((size_t)(bhI * 8 + qtile) * 4 + wv) * 2 + mtF) * 2 + kc) * 512
                       + (qF * 16 + l15F) * 8 + j;
          Qhf[idx] = hi; Qlf[idx] = lo;
        } else {
          int ktile = tt >> 7, fkt = (tt >> 4) & 7, l15F = tt & 15;
          size_t idx = (((size_t)(bhI * 8 + ktile) * 8 + fkt) * 2 + kc) * 512
                       + (qF * 16 + l15F) * 8 + j;
          Khf[idx] = hi; Klf[idx] = lo;
        }
      }
}

// ---------------- flash attention (S^T, frag-major, 64-key dbuf tiles) -------
// grid = 1024, block = 256 (4 waves x 32 q-rows). qt = bid>>7, bh = bid&127
// (same-bh blocks 128 apart => same XCD => K/V L2-shared).
// 16 tiles of 64 keys; LDS double-buffered (2 x 24KB); barrier THEN prefetch
// order so each barrier's vmcnt(0) drain finds tile j's loads one full
// compute phase old.
__global__ __launch_bounds__(256, 3) void attn_kernel(
    const u16* __restrict__ Qhf, const u16* __restrict__ Qlf,
    const u16* __restrict__ Khf, const u16* __restrict__ Klf,
    const u16* __restrict__ Vf, u16* __restrict__ O)
{
  __shared__ __attribute__((aligned(16))) u16 lKh[2][4096], lKl[2][4096], lV[2][4096];
  const int tid = threadIdx.x, lane = tid & 63, wave = tid >> 6;
  const int quad = lane >> 4, l15 = lane & 15;
  const int qt = blockIdx.x >> 7, bh = blockIdx.x & 127;
  const int b = bh >> 4, h = bh & 15;
  const int q0 = qt * 128;
  const float BETA = 0.18033688011112042f;   // (1/sqrt(64)) * log2(e)

  bf16x8 qh[2][2], ql[2][2];
  { // stage Q through the (not-yet-used) double buffers as 16KB scratch
    size_t qbase = (size_t)(bh * 8 + qt) * 8192 + wave * 2048 + lane * 8;
    u16* sh = &lKh[0][0];  u16* sl = &lKl[0][0];   // flattened 2x4096
#pragma unroll
    for (int i = 0; i < 4; i++){
      gld16(Qhf + qbase + i * 512, sh + wave * 2048 + i * 512);
      gld16(Qlf + qbase + i * 512, sl + wave * 2048 + i * 512);
    }
    __syncthreads();
#pragma unroll
    for (int mt = 0; mt < 2; mt++)
#pragma unroll
      for (int kc = 0; kc < 2; kc++){
        int off = wave * 2048 + (mt * 2 + kc) * 512 + lane * 8;
        qh[mt][kc] = ldsfrag(sh + off);
        ql[mt][kc] = ldsfrag(sl + off);
      }
    __syncthreads();
  }

  float m_i[2] = {-3.0e38f, -3.0e38f}, l_i[2] = {0.0f, 0.0f};
  f32x4 o_acc[2][4];
#pragma unroll
  for (int mt = 0; mt < 2; mt++)
#pragma unroll
    for (int nd = 0; nd < 4; nd++) o_acc[mt][nd] = (f32x4)0.0f;

  const size_t pan = (size_t)bh * 65536;   // per-bh K/Kl/V panel base (u16)
  // prefetch tile 0 into buf 0 (2 chunks per array per wave)
#pragma unroll
  for (int i = 0; i < 2; i++){
    int c = wave * 2 + i;                  // 0..7 chunks of 512 u16
    gld16(Khf + pan + c * 512 + lane * 8, &lKh[0][c * 512]);
    gld16(Klf + pan + c * 512 + lane * 8, &lKl[0][c * 512]);
    gld16(Vf  + pan + c * 512 + lane * 8, &lV [0][c * 512]);
  }

#pragma unroll 1
  for (int j = 0; j < 16; j++){
    const int cur = j & 1;
    __syncthreads();                       // drains tile-j loads (1 phase old)
    if (j < 15){
      size_t nb = pan + (size_t)(j + 1) * 4096;
      const int nxt = cur ^ 1;
#pragma unroll
      for (int i = 0; i < 2; i++){
        int c = wave * 2 + i;
        gld16(Khf + nb + c * 512 + lane * 8, &lKh[nxt][c * 512]);
        gld16(Klf + nb + c * 512 + lane * 8, &lKl[nxt][c * 512]);
        gld16(Vf  + nb + c * 512 + lane * 8, &lV [nxt][c * 512]);
      }
    }

    // S^T = K.Q^T for 64 keys (A = K frags, B = Q frags), 3-term split
    f32x4 s[2][4];
#pragma unroll
    for (int qt2 = 0; qt2 < 2; qt2++)
#pragma unroll
      for (int f4 = 0; f4 < 4; f4++) s[qt2][f4] = (f32x4)0.0f;
#pragma unroll
    for (int f4 = 0; f4 < 4; f4++){
      int aoff = f4 * 1024 + lane * 8;     // lane-linear, conflict-free
      bf16x8 kh0 = ldsfrag(&lKh[cur][aoff]);
      bf16x8 kh1 = ldsfrag(&lKh[cur][aoff + 512]);
      bf16x8 kl0 = ldsfrag(&lKl[cur][aoff]);
      bf16x8 kl1 = ldsfrag(&lKl[cur][aoff + 512]);
#pragma unroll
      for (int qt2 = 0; qt2 < 2; qt2++){
        s[qt2][f4] = MFMA16(kl0, qh[qt2][0], s[qt2][f4]);
        s[qt2][f4] = MFMA16(kl1, qh[qt2][1], s[qt2][f4]);
        s[qt2][f4] = MFMA16(kh0, ql[qt2][0], s[qt2][f4]);
        s[qt2][f4] = MFMA16(kh1, ql[qt2][1], s[qt2][f4]);
        s[qt2][f4] = MFMA16(kh0, qh[qt2][0], s[qt2][f4]);
        s[qt2][f4] = MFMA16(kh1, qh[qt2][1], s[qt2][f4]);
      }
    }

    // online softmax merge (lane l15 = q; 16 logits in-lane)
    float alpha[2];
#pragma unroll
    for (int qt2 = 0; qt2 < 2; qt2++){
      f32x4 mv = s[qt2][0];
#pragma unroll
      for (int f4 = 1; f4 < 4; f4++){
        mv[0] = fmaxf(mv[0], s[qt2][f4][0]); mv[1] = fmaxf(mv[1], s[qt2][f4][1]);
        mv[2] = fmaxf(mv[2], s[qt2][f4][2]); mv[3] = fmaxf(mv[3], s[qt2][f4][3]);
      }
      float mx = fmaxf(fmaxf(mv[0], mv[1]), fmaxf(mv[2], mv[3]));
      mx = fmaxf(mx, __shfl_xor(mx, 16));
      mx = fmaxf(mx, __shfl_xor(mx, 32));
      float mn = fmaxf(m_i[qt2], mx);
      alpha[qt2] = __builtin_amdgcn_exp2f((m_i[qt2] - mn) * BETA);
      m_i[qt2] = mn;
      float mb = mn * BETA;
      f32x4 ps = (f32x4)0.0f;
#pragma unroll
      for (int f4 = 0; f4 < 4; f4++)
#pragma unroll
        for (int r = 0; r < 4; r++){
          float p = __builtin_amdgcn_exp2f(s[qt2][f4][r] * BETA - mb);
          s[qt2][f4][r] = p;
          ps[r] += p;                      // 4 independent partial chains
        }
      float rs = (ps[0] + ps[1]) + (ps[2] + ps[3]);
      rs += __shfl_xor(rs, 16);
      rs += __shfl_xor(rs, 32);
      l_i[qt2] = l_i[qt2] * alpha[qt2] + rs;
    }

    // rescale O (alpha at lane l15=q -> broadcast to O row layout)
#pragma unroll
    for (int mt = 0; mt < 2; mt++)
#pragma unroll
      for (int r = 0; r < 4; r++){
        float ar = __shfl(alpha[mt], quad * 4 + r);
#pragma unroll
        for (int nd = 0; nd < 4; nd++) o_acc[mt][nd][r] *= ar;
      }

    // PV via 16x16x16 MFMA; P already in A-frag layout; V lane-linear b64
#pragma unroll
    for (int f4 = 0; f4 < 4; f4++){
      s16x4 vb[4];
#pragma unroll
      for (int nd = 0; nd < 4; nd++)
        vb[nd] = __builtin_bit_cast(s16x4,
                   *(const u16x4*)&lV[cur][(f4 * 4 + nd) * 256 + lane * 4]);
#pragma unroll
      for (int qt2 = 0; qt2 < 2; qt2++){
        u32x2 pd;
        pd[0] = packhi(s[qt2][f4][1], s[qt2][f4][0]);
        pd[1] = packhi(s[qt2][f4][3], s[qt2][f4][2]);
        s16x4 pa = __builtin_bit_cast(s16x4, pd);
#pragma unroll
        for (int nd = 0; nd < 4; nd++)
          o_acc[qt2][nd] = MFMA16K16(pa, vb[nd], o_acc[qt2][nd]);
      }
    }
  }

#pragma unroll
  for (int mt = 0; mt < 2; mt++)
#pragma unroll
    for (int r = 0; r < 4; r++){
      float lr = __shfl(l_i[mt], quad * 4 + r);
      float inv = 1.0f / lr;
      int t = q0 + wave * 32 + mt * 16 + quad * 4 + r;
      size_t rowoff = (size_t)(b * 1024 + t) * 1024 + h * 64;
#pragma unroll
      for (int nd = 0; nd < 4; nd++)
        O[rowoff + nd * 16 + l15] = f2b(o_acc[mt][nd][r] * inv);
    }
}

// ---------------- launcher ----------------
extern "C" void kernel_launch(void* const* d_in, const int* in_sizes, int n_in,
                              void* d_out, int out_size, void* d_ws, size_t ws_size,
                              hipStream_t stream)
{
  const float* x  = (const float*)d_in[0];
  const float* Wq = (const float*)d_in[1];
  const float* Wk = (const float*)d_in[2];
  const float* Wv = (const float*)d_in[3];
  const float* Wp = (const float*)d_in[4];
  float* out = (float*)d_out;
  char* ws = (char*)d_ws;
  const size_t MB = 1024 * 1024;
  // workspace map (peak 124 MB):
  u16* xh   = (u16*)(ws + 0);        // 16MB; reused as O after V-GEMM
  u16* xl   = (u16*)(ws + 16 * MB);  // 16MB
  u16* wqkh = (u16*)(ws + 32 * MB);  // 4MB  [2048][1024]
  u16* wqkl = (u16*)(ws + 36 * MB);  // 4MB
  u16* wvt  = (u16*)(ws + 40 * MB);  // 2MB
  u16* wpt  = (u16*)(ws + 42 * MB);  // 2MB
  u16* Qhf  = (u16*)(ws + 44 * MB);  // 16MB frag-major Q hi
  u16* Qlf  = (u16*)(ws + 60 * MB);  // 16MB frag-major Q lo
  u16* Khf  = (u16*)(ws + 76 * MB);  // 16MB frag-major K hi
  u16* Klf  = (u16*)(ws + 92 * MB);  // 16MB frag-major K lo
  u16* Vf   = (u16*)(ws + 108 * MB); // 16MB frag-major V
  u16* obuf = xh;
  (void)in_sizes; (void)n_in; (void)out_size; (void)ws_size;

  split_x_kernel<<<4096, 256, 0, stream>>>(x, xh, xl, 8 * 1024 * 1024);
  transpose4_kernel<<<dim3(32, 32, 4), dim3(32, 8), 0, stream>>>(
      Wq, Wk, Wv, Wp, wqkh, wqkl, wqkh + 1024 * 1024, wqkl + 1024 * 1024, wvt, wpt);
  gemm_qk_kernel<<<dim3(32, 8), 512, 0, stream>>>(xh, xl, wqkh, wqkl,
                                                  Qhf, Qlf, Khf, Klf, 8192, 2048, 1024);
  gemm_bt_kernel<2><<<dim3(64, 8), 256, 0, stream>>>(xh, wvt, (void*)Vf, 8192, 1024, 1024);
  attn_kernel<<<1024, 256, 0, stream>>>(Qhf, Qlf, Khf, Klf, Vf, obuf);
  gemm_bt_kernel<0><<<dim3(64, 8), 256, 0, stream>>>(obuf, wpt, (void*)out, 8192, 1024, 1024);
}